// Round 1
// baseline (46.384 us; speedup 1.0000x reference)
//
#include <hip/hip_runtime.h>

// DYSPN fused kernel.
// out[b,h,w] = (G + att3)*cur/(S'+eps) + (1 - S_ppt/(S'+eps))*coarse
// where for k = i*7+j (k != 24, since CENTER_MASK kills the center tap):
//   S_ppt = sum_k att[IDX[k]](h,w) * aff[k](h,w)            + att3(h,w)
//   S'    = sum_k att[IDX[k]](h,w) * |aff[k](h,w)|          + att3(h,w)
//   G     = sum_k att[IDX[k]](y,x) * aff[k](y,x),  (y,x)=(h+3-i, w+3-j), in-bounds only
// Identity used: fold7(kernel * unfold7(x))[h,w] == x[h,w] * sum_k kernel[k, h+3-i, w+3-j].

__global__ __launch_bounds__(256) void dyspn_kernel(
    const float* __restrict__ aff,    // [B,49,H,W]
    const float* __restrict__ attn,   // [B,4,H,W]
    const float* __restrict__ cur,    // [B,1,H,W]
    const float* __restrict__ coarse, // [B,1,H,W]
    float* __restrict__ out)          // [B,1,H,W]
{
    constexpr int H = 256, W = 256;
    constexpr int HW = H * W;
    static constexpr int IDX[49] = {
        0,0,0,0,0,0,0,
        0,1,1,1,1,1,0,
        0,1,2,2,2,1,0,
        0,1,2,3,2,1,0,
        0,1,2,2,2,1,0,
        0,1,1,1,1,1,0,
        0,0,0,0,0,0,0};

    // XCD-aware bijective swizzle: 4096 blocks, 8 XCDs -> 512 contiguous
    // (b,h) rows per XCD so the +-3 row halo stays inside one XCD's L2.
    int bid = blockIdx.x;
    int logical = ((bid & 7) << 9) | (bid >> 3);
    int b = logical >> 8;      // batch
    int h = logical & 255;     // row
    int w = threadIdx.x;       // col

    const float* __restrict__ affb = aff  + (size_t)b * 49 * HW;
    const float* __restrict__ attb = attn + (size_t)b * 4  * HW;
    const int p = h * W + w;

    float at[4];
    at[0] = attb[p];
    at[1] = attb[HW + p];
    at[2] = attb[2 * HW + p];
    at[3] = attb[3 * HW + p];

    float s_ppt = 0.f, s_pr = 0.f, G = 0.f;

#pragma unroll
    for (int k = 0; k < 49; ++k) {
        if (k == 24) continue;                 // center tap masked (IDX==3)
        const int i = k / 7;                   // compile-time after unroll
        const int j = k % 7;
        const int idx = IDX[k];
        // Own-pixel contribution to S_ppt / S'
        float a = affb[k * HW + p];
        float wgt = at[idx];
        s_ppt = fmaf(wgt, a, s_ppt);
        s_pr  = fmaf(wgt, fabsf(a), s_pr);
        // Shifted contribution to G (fold zero-padding = bounds check)
        int y = h + 3 - i;
        int x = w + 3 - j;
        if ((unsigned)y < (unsigned)H && (unsigned)x < (unsigned)W) {
            int q = y * W + x;
            G = fmaf(attb[idx * HW + q], affb[k * HW + q], G);
        }
    }

    const float att_self = at[3];
    s_ppt += att_self;
    s_pr  += att_self;
    const float inv = 1.0f / (s_pr + 1e-6f);
    const size_t pb = (size_t)b * HW + p;
    out[pb] = (G + att_self) * cur[pb] * inv + (1.f - s_ppt * inv) * coarse[pb];
}

extern "C" void kernel_launch(void* const* d_in, const int* in_sizes, int n_in,
                              void* d_out, int out_size, void* d_ws, size_t ws_size,
                              hipStream_t stream) {
    const float* aff    = (const float*)d_in[0];
    const float* attn   = (const float*)d_in[1];
    const float* cur    = (const float*)d_in[2];
    const float* coarse = (const float*)d_in[3];
    float* out = (float*)d_out;

    dim3 grid(16 * 256);   // B * H rows
    dim3 block(256);       // one thread per column
    hipLaunchKernelGGL(dyspn_kernel, grid, block, 0, stream,
                       aff, attn, cur, coarse, out);
}